// Round 7
// baseline (566.439 us; speedup 1.0000x reference)
//
#include <hip/hip_runtime.h>
#include <hip/hip_bf16.h>
#include <math.h>

// NeuralCache, all-MFMA transposed formulation. R14 = R12 + two latency cuts
// (occupancy is pinned: 120 regs = 4 waves/SIMD; R13 proved the 5-wave LDS
// path dead -- DS pipe saturates at ~15 wave-wide ds_read_b128/tile).
// 1) next-group prime at j==3: recompute hash/np from the group-ahead
//    prefetched pos/nrm (overwriting dead idxb/np0/np1 -- zero new regs), so
//    the (j+1)&3 wrap-prefetch primes next group's tile 0 one tile early.
//    Kills the ~260cy group-top bpermute->gather stall.
// 2) deferred sigmoid, interleaved into L2: tile j's sigmoid (3 exp, 3 add,
//    3 rcp on lg_prev) executes between the 8 MFMAs of tile j+1's L2 block
//    (independent regs, separate pipes -> free issue slots); store after L3;
//    tile-3 sigmoid in a per-group epilogue. +8 VGPR (lg_prev, s0-2, premul).
// Carried from R12: 64 points/wave front-end, ds_bpermute broadcast into
// four 16-point MFMA tiles, one-tile-ahead emb prefetch, packed-int ReLU,
// lean sigmoid ops, weights pinned in AGPRs, biases/zero C-init in VGPRs,
// s_nop hazard spacing (layouts verified m89/m118-m122).
// Grid: 1024 blocks x 4 waves = 4096 waves = 16 groups/wave, 4 waves/SIMD.

typedef __attribute__((ext_vector_type(4)))  float        float4v;
typedef __attribute__((ext_vector_type(4)))  unsigned int uint4v;

#define WSF_OFF   0
#define WSB_OFF   (14 * 64 * 16)            // after 14 weight frags
#define EMB_OFF   (WSB_OFF + 5 * 64 * 16)   // after 5 bias frags
// embbf: 4096 rows x 16 bf16 = 32 B/row, 128 KiB

static __device__ __forceinline__ unsigned pack2_rne(float a, float b) {
    __hip_bfloat16 ha = __float2bfloat16(a), hb = __float2bfloat16(b);
    unsigned short ua = *reinterpret_cast<unsigned short*>(&ha);
    unsigned short ub = *reinterpret_cast<unsigned short*>(&hb);
    return (unsigned)ua | ((unsigned)ub << 16);
}
static __device__ __forceinline__ uint4v mk_frag_u(const float* v) {
    uint4v u;
    u.x = pack2_rne(v[0], v[1]); u.y = pack2_rne(v[2], v[3]);
    u.z = pack2_rne(v[4], v[5]); u.w = pack2_rne(v[6], v[7]);
    return u;
}
// hot-loop pack: single HW instruction, RNE, low = a, high = b
static __device__ __forceinline__ unsigned cvtpk(float a, float b) {
    unsigned r;
    asm("v_cvt_pk_bf16_f32 %0, %1, %2" : "=v"(r) : "v"(a), "v"(b));
    return r;
}
// packed bf16 ReLU: negative bf16 bit patterns are negative as i16,
// non-negative ones are monotone non-negative -> max_i16(x,0) == relu.
static __device__ __forceinline__ unsigned pkrelu(unsigned x) {
    unsigned r;
    asm("v_pk_max_i16 %0, %1, 0" : "=v"(r) : "v"(x));
    return r;
}

// ---------------- prep: weights -> fragment layout + emb -> bf16 ----------------
__global__ void nc_prep(const float* __restrict__ W1, const float* __restrict__ b1,
                        const float* __restrict__ W2, const float* __restrict__ b2,
                        const float* __restrict__ W3, const float* __restrict__ b3,
                        const float* __restrict__ emb, char* __restrict__ ws)
{
    uint4v*   wsf   = (uint4v*)(ws + WSF_OFF);
    float4v*  wsb   = (float4v*)(ws + WSB_OFF);
    unsigned* embbf = (unsigned*)(ws + EMB_OFF);

    // emb conversion: 4096*16 elems = 32768 dwords (pairs never cross rows)
    const int gtid = blockIdx.x * blockDim.x + threadIdx.x;
    if (gtid < 32768)
        embbf[gtid] = pack2_rne(emb[2 * gtid], emb[2 * gtid + 1]);

    if (blockIdx.x != 0 || threadIdx.x >= 64) return;
    const int lane = threadIdx.x;
    const int m    = lane & 15;
    const int quad = lane >> 4;
    const int qs = m >> 2, rs = m & 3;

    for (int nt = 0; nt < 4; ++nt) {
        const int n = 32 * (nt >> 1) + 8 * qs + 4 * (nt & 1) + rs;
        float v[8];
        for (int j = 0; j < 8; ++j) {
            const int k = quad * 8 + j;
            v[j] = (k < 19) ? W1[k * 64 + n] : (k == 19 ? b1[n] : 0.0f);
        }
        wsf[nt * 64 + lane] = mk_frag_u(v);
    }
    for (int kt = 0; kt < 2; ++kt)
        for (int nt = 0; nt < 4; ++nt) {
            const int n = 32 * (nt >> 1) + 8 * qs + 4 * (nt & 1) + rs;
            float v[8];
            for (int j = 0; j < 8; ++j)
                v[j] = W2[(kt * 32 + quad * 8 + j) * 64 + n];
            wsf[(4 + kt * 4 + nt) * 64 + lane] = mk_frag_u(v);
        }
    for (int kt = 0; kt < 2; ++kt) {
        float v[8];
        for (int j = 0; j < 8; ++j)
            v[j] = (m < 3) ? W3[(kt * 32 + quad * 8 + j) * 3 + m] : 0.0f;
        wsf[(12 + kt) * 64 + lane] = mk_frag_u(v);
    }
    for (int nt = 0; nt < 4; ++nt) {
        const int base = 32 * (nt >> 1) + 8 * quad + 4 * (nt & 1);
        float4v v; v.x = b2[base]; v.y = b2[base+1]; v.z = b2[base+2]; v.w = b2[base+3];
        wsb[nt * 64 + lane] = v;
    }
    float4v v3;
    v3.x = (quad == 0) ? b3[0] : 0.f;
    v3.y = (quad == 0) ? b3[1] : 0.f;
    v3.z = (quad == 0) ? b3[2] : 0.f;
    v3.w = 0.f;
    wsb[4 * 64 + lane] = v3;
}

// ---------------- main ----------------
__global__ __launch_bounds__(256, 4) void nc_mfma12(
    const float* __restrict__ pos, const float* __restrict__ nrm,
    const char* __restrict__ ws, float* __restrict__ out, int npts)
{
    const uint4v*  wsf   = (const uint4v*)(ws + WSF_OFF);
    const float4v* wsb   = (const float4v*)(ws + WSB_OFF);
    const char*    embbf = ws + EMB_OFF;

    const int lane = threadIdx.x & 63;
    const int m    = lane & 15;
    const int quad = lane >> 4;

    // -------- load fragments; pin weights in AGPRs, biases in VGPRs --------
    uint4v w1p[4], w2p[2][4], w3p[2];
    float4v b2p[4], b3p;
    float4v zerof = (float4v){0.f, 0.f, 0.f, 0.f};
    #pragma unroll
    for (int nt = 0; nt < 4; ++nt) w1p[nt] = wsf[nt * 64 + lane];
    #pragma unroll
    for (int kt = 0; kt < 2; ++kt)
        #pragma unroll
        for (int nt = 0; nt < 4; ++nt)
            w2p[kt][nt] = wsf[(4 + kt * 4 + nt) * 64 + lane];
    #pragma unroll
    for (int kt = 0; kt < 2; ++kt) w3p[kt] = wsf[(12 + kt) * 64 + lane];
    #pragma unroll
    for (int nt = 0; nt < 4; ++nt) b2p[nt] = wsb[nt * 64 + lane];
    b3p = wsb[4 * 64 + lane];

    asm volatile("" : "+a"(w1p[0]), "+a"(w1p[1]), "+a"(w1p[2]), "+a"(w1p[3]));
    asm volatile("" : "+a"(w2p[0][0]), "+a"(w2p[0][1]), "+a"(w2p[0][2]), "+a"(w2p[0][3]));
    asm volatile("" : "+a"(w2p[1][0]), "+a"(w2p[1][1]), "+a"(w2p[1][2]), "+a"(w2p[1][3]));
    asm volatile("" : "+a"(w3p[0]), "+a"(w3p[1]));
    asm volatile("" : "+v"(b2p[0]), "+v"(b2p[1]), "+v"(b2p[2]), "+v"(b2p[3]));
    asm volatile("" : "+v"(b3p), "+v"(zerof));

    const int groupsTotal = npts >> 6;                    // 64 points / group
    const int waveId      = blockIdx.x * 4 + (threadIdx.x >> 6);
    const int numWaves    = gridDim.x * 4;

    const int  a0   = m << 2;          // bpermute base byte-addr (src lane m)
    const bool is2  = (quad == 2);
    const int  esel = (quad & 1) << 4; // which 16B half of the 32B emb row

    // -------- prologue: own point's pos/nrm for first group --------
    int g = waveId;
    float p0 = 0.f, p1 = 0.f, p2 = 0.f, n0 = 0.f, n1 = 0.f, n2 = 0.f;
    if (g < groupsTotal) {
        const int pt = g * 64 + lane;
        p0 = pos[3 * pt + 0]; p1 = pos[3 * pt + 1]; p2 = pos[3 * pt + 2];
        n0 = nrm[3 * pt + 0]; n1 = nrm[3 * pt + 1]; n2 = nrm[3 * pt + 2];
    }

    // first group's hash / packed normals (mutable: refreshed at j==3)
    int sx = (int)(p0 * 10.0f), sy = (int)(p1 * 10.0f), sz = (int)(p2 * 10.0f);
    unsigned hh = ((unsigned)sx * 73856093u) ^ ((unsigned)sy * 19349663u)
                ^ ((unsigned)sz * 83492791u);
    int      idxb = (int)((hh & 4095u) << 5);   // byte offset of emb row
    unsigned np0  = cvtpk(n0, n1);
    unsigned np1  = cvtpk(n2, 1.0f);

    // prime tile 0 of first group
    int      eoffc = __builtin_amdgcn_ds_bpermute(a0, idxb);
    unsigned p0c   = (unsigned)__builtin_amdgcn_ds_bpermute(a0, (int)np0);
    unsigned p1c   = (unsigned)__builtin_amdgcn_ds_bpermute(a0, (int)np1);
    uint4v   exc   = *(const uint4v*)(embbf + eoffc + esel);

    float4v lgp = zerof;   // deferred-sigmoid carry (tile j-1's logits)

    for (; g < groupsTotal; g += numWaves) {
        const int base3 = g * 192;     // 3 * 64 * g : dword offset of group in out

        // ---- issue next group's pos/nrm loads (hash for them happens at j==3) ----
        {
            const int tn  = g + numWaves;
            const int ptn = ((tn < groupsTotal) ? tn : g) * 64 + lane;
            p0 = pos[3 * ptn + 0]; p1 = pos[3 * ptn + 1]; p2 = pos[3 * ptn + 2];
            n0 = nrm[3 * ptn + 0]; n1 = nrm[3 * ptn + 1]; n2 = nrm[3 * ptn + 2];
        }

        // ---- four 16-point MFMA tiles, one-tile-ahead prefetch ----
        #pragma unroll 1
        for (int j = 0; j < 4; ++j) {
            // j==3: switch hash/np to NEXT group (its pos/nrm landed long ago)
            // so the wrap-prefetch below primes next group's tile 0.
            if (j == 3) {
                sx = (int)(p0 * 10.0f); sy = (int)(p1 * 10.0f); sz = (int)(p2 * 10.0f);
                hh = ((unsigned)sx * 73856093u) ^ ((unsigned)sy * 19349663u)
                   ^ ((unsigned)sz * 83492791u);
                idxb = (int)((hh & 4095u) << 5);
                np0  = cvtpk(n0, n1);
                np1  = cvtpk(n2, 1.0f);
            }

            // prefetch tile (j+1)&3 (j==3 wraps to NEXT group's tile 0)
            const int bn = a0 + ((((j + 1) & 3)) << 6);
            const int      eoffn = __builtin_amdgcn_ds_bpermute(bn, idxb);
            const unsigned p0n   = (unsigned)__builtin_amdgcn_ds_bpermute(bn, (int)np0);
            const unsigned p1n   = (unsigned)__builtin_amdgcn_ds_bpermute(bn, (int)np1);
            const uint4v   exn   = *(const uint4v*)(embbf + eoffn + esel);

            // quads 0/1: emb halves k=0..7 / k=8..15. quad2 lo: normals.
            // quad2 hi (k20..23) and quad3 (k24..31): finite garbage, A rows are 0.
            uint4v xu;
            xu.x = is2 ? p0c : exc.x;
            xu.y = is2 ? p1c : exc.y;
            xu.z = exc.z;
            xu.w = exc.w;

            // ---- layer 1: 4 MFMAs, A from AGPR, B/C/D in VGPR ----
            float4v h1_0, h1_1, h1_2, h1_3;
            asm("s_nop 1\n\t"
                "v_mfma_f32_16x16x32_bf16 %0, %4, %8, %9\n\t"
                "v_mfma_f32_16x16x32_bf16 %1, %5, %8, %9\n\t"
                "v_mfma_f32_16x16x32_bf16 %2, %6, %8, %9\n\t"
                "v_mfma_f32_16x16x32_bf16 %3, %7, %8, %9\n\t"
                "s_nop 7\n\ts_nop 7"
                : "=&v"(h1_0), "=&v"(h1_1), "=&v"(h1_2), "=&v"(h1_3)
                : "a"(w1p[0]), "a"(w1p[1]), "a"(w1p[2]), "a"(w1p[3]),
                  "v"(xu), "v"(zerof));

            uint4v B10, B11;
            B10.x = pkrelu(cvtpk(h1_0.x, h1_0.y));
            B10.y = pkrelu(cvtpk(h1_0.z, h1_0.w));
            B10.z = pkrelu(cvtpk(h1_1.x, h1_1.y));
            B10.w = pkrelu(cvtpk(h1_1.z, h1_1.w));
            B11.x = pkrelu(cvtpk(h1_2.x, h1_2.y));
            B11.y = pkrelu(cvtpk(h1_2.z, h1_2.w));
            B11.z = pkrelu(cvtpk(h1_3.x, h1_3.y));
            B11.w = pkrelu(cvtpk(h1_3.z, h1_3.w));

            // ---- layer 2: 8 MFMAs with tile j-1's sigmoid interleaved ----
            // (independent regs -> VALU rides in MFMA issue shadow; at j==0
            //  lgp is stale/garbage and the result is never stored)
            const float a0f = lgp.x * -1.44269504f;
            const float a1f = lgp.y * -1.44269504f;
            const float a2f = lgp.z * -1.44269504f;
            float4v h2_0, h2_1, h2_2, h2_3;
            float s0, s1, s2;
            asm("s_nop 1\n\t"
                "v_mfma_f32_16x16x32_bf16 %0, %7, %15, %17\n\t"
                "v_exp_f32 %4, %21\n\t"
                "v_mfma_f32_16x16x32_bf16 %1, %8, %15, %18\n\t"
                "v_exp_f32 %5, %22\n\t"
                "v_mfma_f32_16x16x32_bf16 %2, %9, %15, %19\n\t"
                "v_exp_f32 %6, %23\n\t"
                "v_mfma_f32_16x16x32_bf16 %3, %10, %15, %20\n\t"
                "v_add_f32 %4, 1.0, %4\n\t"
                "v_mfma_f32_16x16x32_bf16 %0, %11, %16, %0\n\t"
                "v_add_f32 %5, 1.0, %5\n\t"
                "v_mfma_f32_16x16x32_bf16 %1, %12, %16, %1\n\t"
                "v_add_f32 %6, 1.0, %6\n\t"
                "v_mfma_f32_16x16x32_bf16 %2, %13, %16, %2\n\t"
                "v_rcp_f32 %4, %4\n\t"
                "v_mfma_f32_16x16x32_bf16 %3, %14, %16, %3\n\t"
                "v_rcp_f32 %5, %5\n\t"
                "v_rcp_f32 %6, %6\n\t"
                "s_nop 7\n\ts_nop 7"
                : "=&v"(h2_0), "=&v"(h2_1), "=&v"(h2_2), "=&v"(h2_3),
                  "=&v"(s0), "=&v"(s1), "=&v"(s2)
                : "a"(w2p[0][0]), "a"(w2p[0][1]), "a"(w2p[0][2]), "a"(w2p[0][3]),
                  "a"(w2p[1][0]), "a"(w2p[1][1]), "a"(w2p[1][2]), "a"(w2p[1][3]),
                  "v"(B10), "v"(B11),
                  "v"(b2p[0]), "v"(b2p[1]), "v"(b2p[2]), "v"(b2p[3]),
                  "v"(a0f), "v"(a1f), "v"(a2f));

            uint4v B20, B21;
            B20.x = pkrelu(cvtpk(h2_0.x, h2_0.y));
            B20.y = pkrelu(cvtpk(h2_0.z, h2_0.w));
            B20.z = pkrelu(cvtpk(h2_1.x, h2_1.y));
            B20.w = pkrelu(cvtpk(h2_1.z, h2_1.w));
            B21.x = pkrelu(cvtpk(h2_2.x, h2_2.y));
            B21.y = pkrelu(cvtpk(h2_2.z, h2_2.w));
            B21.z = pkrelu(cvtpk(h2_3.x, h2_3.y));
            B21.w = pkrelu(cvtpk(h2_3.z, h2_3.w));

            // ---- layer 3: 2 chained MFMAs (C forwarding) ----
            float4v lg;
            asm("s_nop 1\n\t"
                "v_mfma_f32_16x16x32_bf16 %0, %1, %3, %5\n\t"
                "v_mfma_f32_16x16x32_bf16 %0, %2, %4, %0\n\t"
                "s_nop 7\n\ts_nop 7"
                : "=&v"(lg)
                : "a"(w3p[0]), "a"(w3p[1]), "v"(B20), "v"(B21), "v"(b3p));

            // ---- store tile j-1's sigmoid (quad0 lanes hold point m's channels) ----
            if (j != 0 && quad == 0) {
                float* o = out + base3 + (j - 1) * 48 + 3 * m;
                o[0] = s0; o[1] = s1; o[2] = s2;
            }

            // rotate: logits and prefetched tile
            lgp = lg;
            exc = exn; p0c = p0n; p1c = p1n;
        }

        // ---- group epilogue: tile 3's sigmoid + store ----
        {
            const float a0f = lgp.x * -1.44269504f;
            const float a1f = lgp.y * -1.44269504f;
            const float a2f = lgp.z * -1.44269504f;
            float s0, s1, s2;
            asm("v_exp_f32 %0, %3\n\t"
                "v_exp_f32 %1, %4\n\t"
                "v_exp_f32 %2, %5\n\t"
                "v_add_f32 %0, 1.0, %0\n\t"
                "v_add_f32 %1, 1.0, %1\n\t"
                "v_add_f32 %2, 1.0, %2\n\t"
                "v_rcp_f32 %0, %0\n\t"
                "v_rcp_f32 %1, %1\n\t"
                "v_rcp_f32 %2, %2\n\t"
                "s_nop 0"
                : "=&v"(s0), "=&v"(s1), "=&v"(s2)
                : "v"(a0f), "v"(a1f), "v"(a2f));
            if (quad == 0) {
                float* o = out + base3 + 144 + 3 * m;
                o[0] = s0; o[1] = s1; o[2] = s2;
            }
        }
    }
}

extern "C" void kernel_launch(void* const* d_in, const int* in_sizes, int n_in,
                              void* d_out, int out_size, void* d_ws, size_t ws_size,
                              hipStream_t stream) {
    const float* pos = (const float*)d_in[0];
    const float* nrm = (const float*)d_in[1];
    const float* emb = (const float*)d_in[2];
    const float* W1  = (const float*)d_in[3];
    const float* b1  = (const float*)d_in[4];
    const float* W2  = (const float*)d_in[5];
    const float* b2  = (const float*)d_in[6];
    const float* W3  = (const float*)d_in[7];
    const float* b3  = (const float*)d_in[8];
    float* out = (float*)d_out;

    const int npts = in_sizes[0] / 3;   // 4,194,304

    // prep: 128 blocks x 256 covers 32768 emb dwords; block 0 also does weights
    nc_prep<<<128, 256, 0, stream>>>(W1, b1, W2, b2, W3, b3, emb, (char*)d_ws);
    // 1024 blocks * 4 waves = 4096 waves = 16 groups/wave, 4 waves/SIMD
    nc_mfma12<<<1024, 256, 0, stream>>>(pos, nrm, (const char*)d_ws, out, npts);
}

// Round 8
// 517.092 us; speedup vs baseline: 1.0954x; 1.0954x over previous
//
#include <hip/hip_runtime.h>
#include <hip/hip_bf16.h>
#include <math.h>

// NeuralCache, all-MFMA transposed formulation. R15 = R12 + next-group prime
// ONLY. R14's fused sigmoid||L2 asm block pinned ~46 VGPRs in one statement
// (7 early-clobber outputs + 27 inputs) and blew the 64-VGPR cap -> scratch
// spills (FETCH 474 MB, 454 us) with VGPR_Count still reading 64. Reverted.
// Kept change (register-neutral): hash/np recomputed at j==3 from the
// group-ahead pos/nrm (overwrites the already-loop-carried idxb/np0/np1),
// so the (j+1)&3 wrap-prefetch primes NEXT group's tile 0 one tile early,
// deleting the ~260cy group-top bpermute->gather serial stall. Per-tile
// sigmoid+store restored exactly as R12 (measured 99.4 us, no spills).
// Budget rule learned: R12 sits at 64 VGPR + 56 AGPR = 120/128; any edit
// adding >8 VGPRs of liveness spills. Tripwire: FETCH_SIZE > 60 MB.
// Carried from R12: 64 points/wave front-end, ds_bpermute broadcast into
// four 16-point MFMA tiles, one-tile-ahead emb prefetch, packed-int ReLU,
// lean sigmoid, weights pinned in AGPRs, biases/zero C-init in VGPRs,
// s_nop hazard spacing (layouts verified m89/m118-m122).
// Grid: 1024 blocks x 4 waves = 4096 waves = 16 groups/wave, 4 waves/SIMD.

typedef __attribute__((ext_vector_type(4)))  float        float4v;
typedef __attribute__((ext_vector_type(4)))  unsigned int uint4v;

#define WSF_OFF   0
#define WSB_OFF   (14 * 64 * 16)            // after 14 weight frags
#define EMB_OFF   (WSB_OFF + 5 * 64 * 16)   // after 5 bias frags
// embbf: 4096 rows x 16 bf16 = 32 B/row, 128 KiB

static __device__ __forceinline__ unsigned pack2_rne(float a, float b) {
    __hip_bfloat16 ha = __float2bfloat16(a), hb = __float2bfloat16(b);
    unsigned short ua = *reinterpret_cast<unsigned short*>(&ha);
    unsigned short ub = *reinterpret_cast<unsigned short*>(&hb);
    return (unsigned)ua | ((unsigned)ub << 16);
}
static __device__ __forceinline__ uint4v mk_frag_u(const float* v) {
    uint4v u;
    u.x = pack2_rne(v[0], v[1]); u.y = pack2_rne(v[2], v[3]);
    u.z = pack2_rne(v[4], v[5]); u.w = pack2_rne(v[6], v[7]);
    return u;
}
// hot-loop pack: single HW instruction, RNE, low = a, high = b
static __device__ __forceinline__ unsigned cvtpk(float a, float b) {
    unsigned r;
    asm("v_cvt_pk_bf16_f32 %0, %1, %2" : "=v"(r) : "v"(a), "v"(b));
    return r;
}
// packed bf16 ReLU: negative bf16 bit patterns are negative as i16,
// non-negative ones are monotone non-negative -> max_i16(x,0) == relu.
static __device__ __forceinline__ unsigned pkrelu(unsigned x) {
    unsigned r;
    asm("v_pk_max_i16 %0, %1, 0" : "=v"(r) : "v"(x));
    return r;
}

// ---------------- prep: weights -> fragment layout + emb -> bf16 ----------------
__global__ void nc_prep(const float* __restrict__ W1, const float* __restrict__ b1,
                        const float* __restrict__ W2, const float* __restrict__ b2,
                        const float* __restrict__ W3, const float* __restrict__ b3,
                        const float* __restrict__ emb, char* __restrict__ ws)
{
    uint4v*   wsf   = (uint4v*)(ws + WSF_OFF);
    float4v*  wsb   = (float4v*)(ws + WSB_OFF);
    unsigned* embbf = (unsigned*)(ws + EMB_OFF);

    // emb conversion: 4096*16 elems = 32768 dwords (pairs never cross rows)
    const int gtid = blockIdx.x * blockDim.x + threadIdx.x;
    if (gtid < 32768)
        embbf[gtid] = pack2_rne(emb[2 * gtid], emb[2 * gtid + 1]);

    if (blockIdx.x != 0 || threadIdx.x >= 64) return;
    const int lane = threadIdx.x;
    const int m    = lane & 15;
    const int quad = lane >> 4;
    const int qs = m >> 2, rs = m & 3;

    for (int nt = 0; nt < 4; ++nt) {
        const int n = 32 * (nt >> 1) + 8 * qs + 4 * (nt & 1) + rs;
        float v[8];
        for (int j = 0; j < 8; ++j) {
            const int k = quad * 8 + j;
            v[j] = (k < 19) ? W1[k * 64 + n] : (k == 19 ? b1[n] : 0.0f);
        }
        wsf[nt * 64 + lane] = mk_frag_u(v);
    }
    for (int kt = 0; kt < 2; ++kt)
        for (int nt = 0; nt < 4; ++nt) {
            const int n = 32 * (nt >> 1) + 8 * qs + 4 * (nt & 1) + rs;
            float v[8];
            for (int j = 0; j < 8; ++j)
                v[j] = W2[(kt * 32 + quad * 8 + j) * 64 + n];
            wsf[(4 + kt * 4 + nt) * 64 + lane] = mk_frag_u(v);
        }
    for (int kt = 0; kt < 2; ++kt) {
        float v[8];
        for (int j = 0; j < 8; ++j)
            v[j] = (m < 3) ? W3[(kt * 32 + quad * 8 + j) * 3 + m] : 0.0f;
        wsf[(12 + kt) * 64 + lane] = mk_frag_u(v);
    }
    for (int nt = 0; nt < 4; ++nt) {
        const int base = 32 * (nt >> 1) + 8 * quad + 4 * (nt & 1);
        float4v v; v.x = b2[base]; v.y = b2[base+1]; v.z = b2[base+2]; v.w = b2[base+3];
        wsb[nt * 64 + lane] = v;
    }
    float4v v3;
    v3.x = (quad == 0) ? b3[0] : 0.f;
    v3.y = (quad == 0) ? b3[1] : 0.f;
    v3.z = (quad == 0) ? b3[2] : 0.f;
    v3.w = 0.f;
    wsb[4 * 64 + lane] = v3;
}

// ---------------- main ----------------
__global__ __launch_bounds__(256, 4) void nc_mfma13(
    const float* __restrict__ pos, const float* __restrict__ nrm,
    const char* __restrict__ ws, float* __restrict__ out, int npts)
{
    const uint4v*  wsf   = (const uint4v*)(ws + WSF_OFF);
    const float4v* wsb   = (const float4v*)(ws + WSB_OFF);
    const char*    embbf = ws + EMB_OFF;

    const int lane = threadIdx.x & 63;
    const int m    = lane & 15;
    const int quad = lane >> 4;

    // -------- load fragments; pin weights in AGPRs, biases in VGPRs --------
    uint4v w1p[4], w2p[2][4], w3p[2];
    float4v b2p[4], b3p;
    float4v zerof = (float4v){0.f, 0.f, 0.f, 0.f};
    #pragma unroll
    for (int nt = 0; nt < 4; ++nt) w1p[nt] = wsf[nt * 64 + lane];
    #pragma unroll
    for (int kt = 0; kt < 2; ++kt)
        #pragma unroll
        for (int nt = 0; nt < 4; ++nt)
            w2p[kt][nt] = wsf[(4 + kt * 4 + nt) * 64 + lane];
    #pragma unroll
    for (int kt = 0; kt < 2; ++kt) w3p[kt] = wsf[(12 + kt) * 64 + lane];
    #pragma unroll
    for (int nt = 0; nt < 4; ++nt) b2p[nt] = wsb[nt * 64 + lane];
    b3p = wsb[4 * 64 + lane];

    asm volatile("" : "+a"(w1p[0]), "+a"(w1p[1]), "+a"(w1p[2]), "+a"(w1p[3]));
    asm volatile("" : "+a"(w2p[0][0]), "+a"(w2p[0][1]), "+a"(w2p[0][2]), "+a"(w2p[0][3]));
    asm volatile("" : "+a"(w2p[1][0]), "+a"(w2p[1][1]), "+a"(w2p[1][2]), "+a"(w2p[1][3]));
    asm volatile("" : "+a"(w3p[0]), "+a"(w3p[1]));
    asm volatile("" : "+v"(b2p[0]), "+v"(b2p[1]), "+v"(b2p[2]), "+v"(b2p[3]));
    asm volatile("" : "+v"(b3p), "+v"(zerof));

    const int groupsTotal = npts >> 6;                    // 64 points / group
    const int waveId      = blockIdx.x * 4 + (threadIdx.x >> 6);
    const int numWaves    = gridDim.x * 4;

    const int  a0   = m << 2;          // bpermute base byte-addr (src lane m)
    const bool is2  = (quad == 2);
    const int  esel = (quad & 1) << 4; // which 16B half of the 32B emb row

    // -------- prologue: own point's pos/nrm for first group --------
    int g = waveId;
    float p0 = 0.f, p1 = 0.f, p2 = 0.f, n0 = 0.f, n1 = 0.f, n2 = 0.f;
    if (g < groupsTotal) {
        const int pt = g * 64 + lane;
        p0 = pos[3 * pt + 0]; p1 = pos[3 * pt + 1]; p2 = pos[3 * pt + 2];
        n0 = nrm[3 * pt + 0]; n1 = nrm[3 * pt + 1]; n2 = nrm[3 * pt + 2];
    }

    // first group's hash / packed normals (mutable: refreshed at j==3)
    int sx = (int)(p0 * 10.0f), sy = (int)(p1 * 10.0f), sz = (int)(p2 * 10.0f);
    unsigned hh = ((unsigned)sx * 73856093u) ^ ((unsigned)sy * 19349663u)
                ^ ((unsigned)sz * 83492791u);
    int      idxb = (int)((hh & 4095u) << 5);   // byte offset of emb row
    unsigned np0  = cvtpk(n0, n1);
    unsigned np1  = cvtpk(n2, 1.0f);

    // prime tile 0 of first group
    int      eoffc = __builtin_amdgcn_ds_bpermute(a0, idxb);
    unsigned p0c   = (unsigned)__builtin_amdgcn_ds_bpermute(a0, (int)np0);
    unsigned p1c   = (unsigned)__builtin_amdgcn_ds_bpermute(a0, (int)np1);
    uint4v   exc   = *(const uint4v*)(embbf + eoffc + esel);

    for (; g < groupsTotal; g += numWaves) {
        const int base3 = g * 192;     // 3 * 64 * g : dword offset of group in out

        // ---- issue next group's pos/nrm loads (their hash happens at j==3) ----
        {
            const int tn  = g + numWaves;
            const int ptn = ((tn < groupsTotal) ? tn : g) * 64 + lane;
            p0 = pos[3 * ptn + 0]; p1 = pos[3 * ptn + 1]; p2 = pos[3 * ptn + 2];
            n0 = nrm[3 * ptn + 0]; n1 = nrm[3 * ptn + 1]; n2 = nrm[3 * ptn + 2];
        }

        // ---- four 16-point MFMA tiles, one-tile-ahead prefetch ----
        #pragma unroll 1
        for (int j = 0; j < 4; ++j) {
            // j==3: switch hash/np to NEXT group (its pos/nrm landed at group
            // top) so the wrap-prefetch below primes next group's tile 0.
            if (j == 3) {
                sx = (int)(p0 * 10.0f); sy = (int)(p1 * 10.0f); sz = (int)(p2 * 10.0f);
                hh = ((unsigned)sx * 73856093u) ^ ((unsigned)sy * 19349663u)
                   ^ ((unsigned)sz * 83492791u);
                idxb = (int)((hh & 4095u) << 5);
                np0  = cvtpk(n0, n1);
                np1  = cvtpk(n2, 1.0f);
            }

            // prefetch tile (j+1)&3 (j==3 wraps to NEXT group's tile 0)
            const int bn = a0 + ((((j + 1) & 3)) << 6);
            const int      eoffn = __builtin_amdgcn_ds_bpermute(bn, idxb);
            const unsigned p0n   = (unsigned)__builtin_amdgcn_ds_bpermute(bn, (int)np0);
            const unsigned p1n   = (unsigned)__builtin_amdgcn_ds_bpermute(bn, (int)np1);
            const uint4v   exn   = *(const uint4v*)(embbf + eoffn + esel);

            // quads 0/1: emb halves k=0..7 / k=8..15. quad2 lo: normals.
            // quad2 hi (k20..23) and quad3 (k24..31): finite garbage, A rows are 0.
            uint4v xu;
            xu.x = is2 ? p0c : exc.x;
            xu.y = is2 ? p1c : exc.y;
            xu.z = exc.z;
            xu.w = exc.w;

            // ---- layer 1: 4 MFMAs, A from AGPR, B/C/D in VGPR ----
            float4v h1_0, h1_1, h1_2, h1_3;
            asm("s_nop 1\n\t"
                "v_mfma_f32_16x16x32_bf16 %0, %4, %8, %9\n\t"
                "v_mfma_f32_16x16x32_bf16 %1, %5, %8, %9\n\t"
                "v_mfma_f32_16x16x32_bf16 %2, %6, %8, %9\n\t"
                "v_mfma_f32_16x16x32_bf16 %3, %7, %8, %9\n\t"
                "s_nop 7\n\ts_nop 7"
                : "=&v"(h1_0), "=&v"(h1_1), "=&v"(h1_2), "=&v"(h1_3)
                : "a"(w1p[0]), "a"(w1p[1]), "a"(w1p[2]), "a"(w1p[3]),
                  "v"(xu), "v"(zerof));

            uint4v B10, B11;
            B10.x = pkrelu(cvtpk(h1_0.x, h1_0.y));
            B10.y = pkrelu(cvtpk(h1_0.z, h1_0.w));
            B10.z = pkrelu(cvtpk(h1_1.x, h1_1.y));
            B10.w = pkrelu(cvtpk(h1_1.z, h1_1.w));
            B11.x = pkrelu(cvtpk(h1_2.x, h1_2.y));
            B11.y = pkrelu(cvtpk(h1_2.z, h1_2.w));
            B11.z = pkrelu(cvtpk(h1_3.x, h1_3.y));
            B11.w = pkrelu(cvtpk(h1_3.z, h1_3.w));

            // ---- layer 2: 8 MFMAs, bias C-init from VGPR ----
            float4v h2_0, h2_1, h2_2, h2_3;
            asm("s_nop 1\n\t"
                "v_mfma_f32_16x16x32_bf16 %0, %4, %12, %14\n\t"
                "v_mfma_f32_16x16x32_bf16 %1, %5, %12, %15\n\t"
                "v_mfma_f32_16x16x32_bf16 %2, %6, %12, %16\n\t"
                "v_mfma_f32_16x16x32_bf16 %3, %7, %12, %17\n\t"
                "v_mfma_f32_16x16x32_bf16 %0, %8, %13, %0\n\t"
                "v_mfma_f32_16x16x32_bf16 %1, %9, %13, %1\n\t"
                "v_mfma_f32_16x16x32_bf16 %2, %10, %13, %2\n\t"
                "v_mfma_f32_16x16x32_bf16 %3, %11, %13, %3\n\t"
                "s_nop 7\n\ts_nop 7"
                : "=&v"(h2_0), "=&v"(h2_1), "=&v"(h2_2), "=&v"(h2_3)
                : "a"(w2p[0][0]), "a"(w2p[0][1]), "a"(w2p[0][2]), "a"(w2p[0][3]),
                  "a"(w2p[1][0]), "a"(w2p[1][1]), "a"(w2p[1][2]), "a"(w2p[1][3]),
                  "v"(B10), "v"(B11),
                  "v"(b2p[0]), "v"(b2p[1]), "v"(b2p[2]), "v"(b2p[3]));

            uint4v B20, B21;
            B20.x = pkrelu(cvtpk(h2_0.x, h2_0.y));
            B20.y = pkrelu(cvtpk(h2_0.z, h2_0.w));
            B20.z = pkrelu(cvtpk(h2_1.x, h2_1.y));
            B20.w = pkrelu(cvtpk(h2_1.z, h2_1.w));
            B21.x = pkrelu(cvtpk(h2_2.x, h2_2.y));
            B21.y = pkrelu(cvtpk(h2_2.z, h2_2.w));
            B21.z = pkrelu(cvtpk(h2_3.x, h2_3.y));
            B21.w = pkrelu(cvtpk(h2_3.z, h2_3.w));

            // ---- layer 3: 2 chained MFMAs (C forwarding) ----
            float4v lg;
            asm("s_nop 1\n\t"
                "v_mfma_f32_16x16x32_bf16 %0, %1, %3, %5\n\t"
                "v_mfma_f32_16x16x32_bf16 %0, %2, %4, %0\n\t"
                "s_nop 7\n\ts_nop 7"
                : "=&v"(lg)
                : "a"(w3p[0]), "a"(w3p[1]), "v"(B20), "v"(B21), "v"(b3p));

            // ---- sigmoid + store (quad0 lanes hold all 3 channels of point m) ----
            // s = rcp(1 + exp2(-x*log2e)); rcp is ~1ulp, well inside tolerance.
            if (quad == 0) {
                const float a0f = lg.x * -1.44269504f;
                const float a1f = lg.y * -1.44269504f;
                const float a2f = lg.z * -1.44269504f;
                float s0, s1, s2;
                asm("v_exp_f32 %0, %3\n\t"
                    "v_exp_f32 %1, %4\n\t"
                    "v_exp_f32 %2, %5\n\t"
                    "v_add_f32 %0, 1.0, %0\n\t"
                    "v_add_f32 %1, 1.0, %1\n\t"
                    "v_add_f32 %2, 1.0, %2\n\t"
                    "v_rcp_f32 %0, %0\n\t"
                    "v_rcp_f32 %1, %1\n\t"
                    "v_rcp_f32 %2, %2\n\t"
                    "s_nop 0"
                    : "=&v"(s0), "=&v"(s1), "=&v"(s2)
                    : "v"(a0f), "v"(a1f), "v"(a2f));
                float* o = out + base3 + j * 48 + 3 * m;
                o[0] = s0; o[1] = s1; o[2] = s2;
            }

            // rotate prefetched tile into current
            exc = exn; p0c = p0n; p1c = p1n;
        }
    }
}

extern "C" void kernel_launch(void* const* d_in, const int* in_sizes, int n_in,
                              void* d_out, int out_size, void* d_ws, size_t ws_size,
                              hipStream_t stream) {
    const float* pos = (const float*)d_in[0];
    const float* nrm = (const float*)d_in[1];
    const float* emb = (const float*)d_in[2];
    const float* W1  = (const float*)d_in[3];
    const float* b1  = (const float*)d_in[4];
    const float* W2  = (const float*)d_in[5];
    const float* b2  = (const float*)d_in[6];
    const float* W3  = (const float*)d_in[7];
    const float* b3  = (const float*)d_in[8];
    float* out = (float*)d_out;

    const int npts = in_sizes[0] / 3;   // 4,194,304

    // prep: 128 blocks x 256 covers 32768 emb dwords; block 0 also does weights
    nc_prep<<<128, 256, 0, stream>>>(W1, b1, W2, b2, W3, b3, emb, (char*)d_ws);
    // 1024 blocks * 4 waves = 4096 waves = 16 groups/wave, 4 waves/SIMD
    nc_mfma13<<<1024, 256, 0, stream>>>(pos, nrm, (const char*)d_ws, out, npts);
}

// Round 9
// 216.721 us; speedup vs baseline: 2.6137x; 2.3860x over previous
//
#include <hip/hip_runtime.h>
#include <hip/hip_bf16.h>
#include <math.h>

// NeuralCache, all-MFMA transposed formulation. R16 = R12 restored EXACTLY
// (the measured-good 99.4us / 64 VGPR / no-spill configuration) + one
// 4-register saving: L1's C operand is the inline constant 0 (legal VOP3P-MAI
// src2, proven to assemble in R13), deleting the zerof quad.
// History: R11 (unroll2), R13 (LDS 5-wave), R14 (fused sigmoid||L2) and
// R15 (cross-group prime) ALL spilled or failed regalloc -- this kernel sits
// at 120/128 regs and every extra-ILP/TLP path costs >=9 regs of liveness.
// Spills are invisible in VGPR_Count (allocator spills under the
// launch_bounds cap instead of growing); FETCH_SIZE is the tripwire.
// Carried from R12: 64 points/wave front-end (per-lane hash/loads),
// ds_bpermute broadcast into four 16-point MFMA tiles, one-tile-ahead emb
// prefetch, packed-int ReLU (v_pk_max_i16 of cvt_pk_bf16), lean sigmoid
// (3x v_exp/v_add/v_rcp), weights pinned in AGPRs, bias C-init in VGPRs,
// s_nop hazard spacing per group (layouts verified m89/m118-m122).
// Grid: 1024 blocks x 4 waves = 4096 waves = 16 groups/wave, 4 waves/SIMD.

typedef __attribute__((ext_vector_type(4)))  float        float4v;
typedef __attribute__((ext_vector_type(4)))  unsigned int uint4v;

#define WSF_OFF   0
#define WSB_OFF   (14 * 64 * 16)            // after 14 weight frags
#define EMB_OFF   (WSB_OFF + 5 * 64 * 16)   // after 5 bias frags
// embbf: 4096 rows x 16 bf16 = 32 B/row, 128 KiB

static __device__ __forceinline__ unsigned pack2_rne(float a, float b) {
    __hip_bfloat16 ha = __float2bfloat16(a), hb = __float2bfloat16(b);
    unsigned short ua = *reinterpret_cast<unsigned short*>(&ha);
    unsigned short ub = *reinterpret_cast<unsigned short*>(&hb);
    return (unsigned)ua | ((unsigned)ub << 16);
}
static __device__ __forceinline__ uint4v mk_frag_u(const float* v) {
    uint4v u;
    u.x = pack2_rne(v[0], v[1]); u.y = pack2_rne(v[2], v[3]);
    u.z = pack2_rne(v[4], v[5]); u.w = pack2_rne(v[6], v[7]);
    return u;
}
// hot-loop pack: single HW instruction, RNE, low = a, high = b
static __device__ __forceinline__ unsigned cvtpk(float a, float b) {
    unsigned r;
    asm("v_cvt_pk_bf16_f32 %0, %1, %2" : "=v"(r) : "v"(a), "v"(b));
    return r;
}
// packed bf16 ReLU: negative bf16 bit patterns are negative as i16,
// non-negative ones are monotone non-negative -> max_i16(x,0) == relu.
static __device__ __forceinline__ unsigned pkrelu(unsigned x) {
    unsigned r;
    asm("v_pk_max_i16 %0, %1, 0" : "=v"(r) : "v"(x));
    return r;
}

// ---------------- prep: weights -> fragment layout + emb -> bf16 ----------------
__global__ void nc_prep(const float* __restrict__ W1, const float* __restrict__ b1,
                        const float* __restrict__ W2, const float* __restrict__ b2,
                        const float* __restrict__ W3, const float* __restrict__ b3,
                        const float* __restrict__ emb, char* __restrict__ ws)
{
    uint4v*   wsf   = (uint4v*)(ws + WSF_OFF);
    float4v*  wsb   = (float4v*)(ws + WSB_OFF);
    unsigned* embbf = (unsigned*)(ws + EMB_OFF);

    // emb conversion: 4096*16 elems = 32768 dwords (pairs never cross rows)
    const int gtid = blockIdx.x * blockDim.x + threadIdx.x;
    if (gtid < 32768)
        embbf[gtid] = pack2_rne(emb[2 * gtid], emb[2 * gtid + 1]);

    if (blockIdx.x != 0 || threadIdx.x >= 64) return;
    const int lane = threadIdx.x;
    const int m    = lane & 15;
    const int quad = lane >> 4;
    const int qs = m >> 2, rs = m & 3;

    for (int nt = 0; nt < 4; ++nt) {
        const int n = 32 * (nt >> 1) + 8 * qs + 4 * (nt & 1) + rs;
        float v[8];
        for (int j = 0; j < 8; ++j) {
            const int k = quad * 8 + j;
            v[j] = (k < 19) ? W1[k * 64 + n] : (k == 19 ? b1[n] : 0.0f);
        }
        wsf[nt * 64 + lane] = mk_frag_u(v);
    }
    for (int kt = 0; kt < 2; ++kt)
        for (int nt = 0; nt < 4; ++nt) {
            const int n = 32 * (nt >> 1) + 8 * qs + 4 * (nt & 1) + rs;
            float v[8];
            for (int j = 0; j < 8; ++j)
                v[j] = W2[(kt * 32 + quad * 8 + j) * 64 + n];
            wsf[(4 + kt * 4 + nt) * 64 + lane] = mk_frag_u(v);
        }
    for (int kt = 0; kt < 2; ++kt) {
        float v[8];
        for (int j = 0; j < 8; ++j)
            v[j] = (m < 3) ? W3[(kt * 32 + quad * 8 + j) * 3 + m] : 0.0f;
        wsf[(12 + kt) * 64 + lane] = mk_frag_u(v);
    }
    for (int nt = 0; nt < 4; ++nt) {
        const int base = 32 * (nt >> 1) + 8 * quad + 4 * (nt & 1);
        float4v v; v.x = b2[base]; v.y = b2[base+1]; v.z = b2[base+2]; v.w = b2[base+3];
        wsb[nt * 64 + lane] = v;
    }
    float4v v3;
    v3.x = (quad == 0) ? b3[0] : 0.f;
    v3.y = (quad == 0) ? b3[1] : 0.f;
    v3.z = (quad == 0) ? b3[2] : 0.f;
    v3.w = 0.f;
    wsb[4 * 64 + lane] = v3;
}

// ---------------- main ----------------
__global__ __launch_bounds__(256, 4) void nc_mfma14(
    const float* __restrict__ pos, const float* __restrict__ nrm,
    const char* __restrict__ ws, float* __restrict__ out, int npts)
{
    const uint4v*  wsf   = (const uint4v*)(ws + WSF_OFF);
    const float4v* wsb   = (const float4v*)(ws + WSB_OFF);
    const char*    embbf = ws + EMB_OFF;

    const int lane = threadIdx.x & 63;
    const int m    = lane & 15;
    const int quad = lane >> 4;

    // -------- load fragments; pin weights in AGPRs, biases in VGPRs --------
    uint4v w1p[4], w2p[2][4], w3p[2];
    float4v b2p[4], b3p;
    #pragma unroll
    for (int nt = 0; nt < 4; ++nt) w1p[nt] = wsf[nt * 64 + lane];
    #pragma unroll
    for (int kt = 0; kt < 2; ++kt)
        #pragma unroll
        for (int nt = 0; nt < 4; ++nt)
            w2p[kt][nt] = wsf[(4 + kt * 4 + nt) * 64 + lane];
    #pragma unroll
    for (int kt = 0; kt < 2; ++kt) w3p[kt] = wsf[(12 + kt) * 64 + lane];
    #pragma unroll
    for (int nt = 0; nt < 4; ++nt) b2p[nt] = wsb[nt * 64 + lane];
    b3p = wsb[4 * 64 + lane];

    asm volatile("" : "+a"(w1p[0]), "+a"(w1p[1]), "+a"(w1p[2]), "+a"(w1p[3]));
    asm volatile("" : "+a"(w2p[0][0]), "+a"(w2p[0][1]), "+a"(w2p[0][2]), "+a"(w2p[0][3]));
    asm volatile("" : "+a"(w2p[1][0]), "+a"(w2p[1][1]), "+a"(w2p[1][2]), "+a"(w2p[1][3]));
    asm volatile("" : "+a"(w3p[0]), "+a"(w3p[1]));
    asm volatile("" : "+v"(b2p[0]), "+v"(b2p[1]), "+v"(b2p[2]), "+v"(b2p[3]));
    asm volatile("" : "+v"(b3p));

    const int groupsTotal = npts >> 6;                    // 64 points / group
    const int waveId      = blockIdx.x * 4 + (threadIdx.x >> 6);
    const int numWaves    = gridDim.x * 4;

    const int  a0   = m << 2;          // bpermute base byte-addr (src lane m)
    const bool is2  = (quad == 2);
    const int  esel = (quad & 1) << 4; // which 16B half of the 32B emb row

    // -------- software prefetch of own point's pos/nrm, one group ahead --------
    int g = waveId;
    float p0 = 0.f, p1 = 0.f, p2 = 0.f, n0 = 0.f, n1 = 0.f, n2 = 0.f;
    if (g < groupsTotal) {
        const int pt = g * 64 + lane;
        p0 = pos[3 * pt + 0]; p1 = pos[3 * pt + 1]; p2 = pos[3 * pt + 2];
        n0 = nrm[3 * pt + 0]; n1 = nrm[3 * pt + 1]; n2 = nrm[3 * pt + 2];
    }

    for (; g < groupsTotal; g += numWaves) {
        const int base3 = g * 192;     // 3 * 64 * g : dword offset of group in out

        // ---- own-point hash (low-12-bit exact in 32-bit arithmetic) ----
        const int sx = (int)(p0 * 10.0f);
        const int sy = (int)(p1 * 10.0f);
        const int sz = (int)(p2 * 10.0f);
        const unsigned h = ((unsigned)sx * 73856093u)
                         ^ ((unsigned)sy * 19349663u)
                         ^ ((unsigned)sz * 83492791u);
        const int idxb = (int)((h & 4095u) << 5);   // byte offset of emb row

        // ---- own-point packed normals (k16,k17) and (k18, bias-one k19) ----
        const unsigned np0 = cvtpk(n0, n1);
        const unsigned np1 = cvtpk(n2, 1.0f);

        // ---- issue next group's pos/nrm loads (hide HBM latency) ----
        {
            const int tn  = g + numWaves;
            const int ptn = ((tn < groupsTotal) ? tn : g) * 64 + lane;
            p0 = pos[3 * ptn + 0]; p1 = pos[3 * ptn + 1]; p2 = pos[3 * ptn + 2];
            n0 = nrm[3 * ptn + 0]; n1 = nrm[3 * ptn + 1]; n2 = nrm[3 * ptn + 2];
        }

        // ---- prime tile-0 broadcast + emb gather ----
        int      eoffc = __builtin_amdgcn_ds_bpermute(a0, idxb);
        unsigned p0c   = (unsigned)__builtin_amdgcn_ds_bpermute(a0, (int)np0);
        unsigned p1c   = (unsigned)__builtin_amdgcn_ds_bpermute(a0, (int)np1);
        uint4v   exc   = *(const uint4v*)(embbf + eoffc + esel);

        // ---- four 16-point MFMA tiles, one-tile-ahead prefetch ----
        #pragma unroll 1
        for (int j = 0; j < 4; ++j) {
            // prefetch tile (j+1)&3 (wraps to tile 0 at j=3; harmless reload)
            const int bn = a0 + ((((j + 1) & 3)) << 6);
            const int      eoffn = __builtin_amdgcn_ds_bpermute(bn, idxb);
            const unsigned p0n   = (unsigned)__builtin_amdgcn_ds_bpermute(bn, (int)np0);
            const unsigned p1n   = (unsigned)__builtin_amdgcn_ds_bpermute(bn, (int)np1);
            const uint4v   exn   = *(const uint4v*)(embbf + eoffn + esel);

            // quads 0/1: emb halves k=0..7 / k=8..15. quad2 lo: normals.
            // quad2 hi (k20..23) and quad3 (k24..31): finite garbage, A rows are 0.
            uint4v xu;
            xu.x = is2 ? p0c : exc.x;
            xu.y = is2 ? p1c : exc.y;
            xu.z = exc.z;
            xu.w = exc.w;

            // ---- layer 1: 4 MFMAs, A from AGPR, C = inline 0 ----
            float4v h1_0, h1_1, h1_2, h1_3;
            asm("s_nop 1\n\t"
                "v_mfma_f32_16x16x32_bf16 %0, %4, %8, 0\n\t"
                "v_mfma_f32_16x16x32_bf16 %1, %5, %8, 0\n\t"
                "v_mfma_f32_16x16x32_bf16 %2, %6, %8, 0\n\t"
                "v_mfma_f32_16x16x32_bf16 %3, %7, %8, 0\n\t"
                "s_nop 7\n\ts_nop 7"
                : "=&v"(h1_0), "=&v"(h1_1), "=&v"(h1_2), "=&v"(h1_3)
                : "a"(w1p[0]), "a"(w1p[1]), "a"(w1p[2]), "a"(w1p[3]),
                  "v"(xu));

            uint4v B10, B11;
            B10.x = pkrelu(cvtpk(h1_0.x, h1_0.y));
            B10.y = pkrelu(cvtpk(h1_0.z, h1_0.w));
            B10.z = pkrelu(cvtpk(h1_1.x, h1_1.y));
            B10.w = pkrelu(cvtpk(h1_1.z, h1_1.w));
            B11.x = pkrelu(cvtpk(h1_2.x, h1_2.y));
            B11.y = pkrelu(cvtpk(h1_2.z, h1_2.w));
            B11.z = pkrelu(cvtpk(h1_3.x, h1_3.y));
            B11.w = pkrelu(cvtpk(h1_3.z, h1_3.w));

            // ---- layer 2: 8 MFMAs, bias C-init from VGPR ----
            float4v h2_0, h2_1, h2_2, h2_3;
            asm("s_nop 1\n\t"
                "v_mfma_f32_16x16x32_bf16 %0, %4, %12, %14\n\t"
                "v_mfma_f32_16x16x32_bf16 %1, %5, %12, %15\n\t"
                "v_mfma_f32_16x16x32_bf16 %2, %6, %12, %16\n\t"
                "v_mfma_f32_16x16x32_bf16 %3, %7, %12, %17\n\t"
                "v_mfma_f32_16x16x32_bf16 %0, %8, %13, %0\n\t"
                "v_mfma_f32_16x16x32_bf16 %1, %9, %13, %1\n\t"
                "v_mfma_f32_16x16x32_bf16 %2, %10, %13, %2\n\t"
                "v_mfma_f32_16x16x32_bf16 %3, %11, %13, %3\n\t"
                "s_nop 7\n\ts_nop 7"
                : "=&v"(h2_0), "=&v"(h2_1), "=&v"(h2_2), "=&v"(h2_3)
                : "a"(w2p[0][0]), "a"(w2p[0][1]), "a"(w2p[0][2]), "a"(w2p[0][3]),
                  "a"(w2p[1][0]), "a"(w2p[1][1]), "a"(w2p[1][2]), "a"(w2p[1][3]),
                  "v"(B10), "v"(B11),
                  "v"(b2p[0]), "v"(b2p[1]), "v"(b2p[2]), "v"(b2p[3]));

            uint4v B20, B21;
            B20.x = pkrelu(cvtpk(h2_0.x, h2_0.y));
            B20.y = pkrelu(cvtpk(h2_0.z, h2_0.w));
            B20.z = pkrelu(cvtpk(h2_1.x, h2_1.y));
            B20.w = pkrelu(cvtpk(h2_1.z, h2_1.w));
            B21.x = pkrelu(cvtpk(h2_2.x, h2_2.y));
            B21.y = pkrelu(cvtpk(h2_2.z, h2_2.w));
            B21.z = pkrelu(cvtpk(h2_3.x, h2_3.y));
            B21.w = pkrelu(cvtpk(h2_3.z, h2_3.w));

            // ---- layer 3: 2 chained MFMAs (C forwarding) ----
            float4v lg;
            asm("s_nop 1\n\t"
                "v_mfma_f32_16x16x32_bf16 %0, %1, %3, %5\n\t"
                "v_mfma_f32_16x16x32_bf16 %0, %2, %4, %0\n\t"
                "s_nop 7\n\ts_nop 7"
                : "=&v"(lg)
                : "a"(w3p[0]), "a"(w3p[1]), "v"(B20), "v"(B21), "v"(b3p));

            // ---- sigmoid + store (quad0 lanes hold all 3 channels of point m) ----
            // s = rcp(1 + exp2(-x*log2e)); rcp is ~1ulp, well inside tolerance.
            if (quad == 0) {
                const float a0f = lg.x * -1.44269504f;
                const float a1f = lg.y * -1.44269504f;
                const float a2f = lg.z * -1.44269504f;
                float s0, s1, s2;
                asm("v_exp_f32 %0, %3\n\t"
                    "v_exp_f32 %1, %4\n\t"
                    "v_exp_f32 %2, %5\n\t"
                    "v_add_f32 %0, 1.0, %0\n\t"
                    "v_add_f32 %1, 1.0, %1\n\t"
                    "v_add_f32 %2, 1.0, %2\n\t"
                    "v_rcp_f32 %0, %0\n\t"
                    "v_rcp_f32 %1, %1\n\t"
                    "v_rcp_f32 %2, %2\n\t"
                    "s_nop 0"
                    : "=&v"(s0), "=&v"(s1), "=&v"(s2)
                    : "v"(a0f), "v"(a1f), "v"(a2f));
                float* o = out + base3 + j * 48 + 3 * m;
                o[0] = s0; o[1] = s1; o[2] = s2;
            }

            // rotate prefetched tile into current
            exc = exn; p0c = p0n; p1c = p1n;
        }
    }
}

extern "C" void kernel_launch(void* const* d_in, const int* in_sizes, int n_in,
                              void* d_out, int out_size, void* d_ws, size_t ws_size,
                              hipStream_t stream) {
    const float* pos = (const float*)d_in[0];
    const float* nrm = (const float*)d_in[1];
    const float* emb = (const float*)d_in[2];
    const float* W1  = (const float*)d_in[3];
    const float* b1  = (const float*)d_in[4];
    const float* W2  = (const float*)d_in[5];
    const float* b2  = (const float*)d_in[6];
    const float* W3  = (const float*)d_in[7];
    const float* b3  = (const float*)d_in[8];
    float* out = (float*)d_out;

    const int npts = in_sizes[0] / 3;   // 4,194,304

    // prep: 128 blocks x 256 covers 32768 emb dwords; block 0 also does weights
    nc_prep<<<128, 256, 0, stream>>>(W1, b1, W2, b2, W3, b3, emb, (char*)d_ws);
    // 1024 blocks * 4 waves = 4096 waves = 16 groups/wave, 4 waves/SIMD
    nc_mfma14<<<1024, 256, 0, stream>>>(pos, nrm, (const char*)d_ws, out, npts);
}